// Round 1
// baseline (456.752 us; speedup 1.0000x reference)
//
#include <hip/hip_runtime.h>

#define NSAMP 400000
#define NBLK  1563   // ceil(400000/256)

// ---- workspace layout (bytes) ----
// 0    : double acc[43]  [0..3]=gsum [4..15]=gz [16..39]=gzz(sym) [40]=loss1sum [41]=energy_sum [42]=lossPart
// 384  : float  P[10]    M00,M01,M02,M11,M12,M22, b0,b1,b2, A
// 1024 : float  G[256]   dec_w3 * dec_w3^T
// 2048 : float  g[16]    dec_w3 * dec_b3
// 2112 : float  bb[1]    ||dec_b3||^2
// 4096 : float4 zbuf[NSAMP]

__device__ __forceinline__ float ftanh(float x) {
    float e = __expf(2.0f * x);
    return 1.0f - __fdividef(2.0f, e + 1.0f);
}

__global__ __launch_bounds__(256) void prep_kernel(const float* __restrict__ dw3,
                                                   const float* __restrict__ db3,
                                                   float* __restrict__ Gm,
                                                   float* __restrict__ gv,
                                                   float* __restrict__ bb) {
    int t = threadIdx.x;
    int a = t >> 4, b = t & 15;
    float s = 0.f;
    for (int j = 0; j < 128; ++j) s += dw3[a * 128 + j] * dw3[b * 128 + j];
    Gm[t] = s;
    if (t < 16) {
        float sg = 0.f;
        for (int j = 0; j < 128; ++j) sg += dw3[t * 128 + j] * db3[j];
        gv[t] = sg;
    }
    if (t == 0) {
        float sbv = 0.f;
        for (int j = 0; j < 128; ++j) sbv += db3[j] * db3[j];
        *bb = sbv;
    }
}

__global__ __launch_bounds__(256) void pass1_kernel(
    const float* __restrict__ x1,
    const float* __restrict__ ew1, const float* __restrict__ eb1,
    const float* __restrict__ ew2, const float* __restrict__ eb2,
    const float* __restrict__ ew3, const float* __restrict__ eb3,
    const float* __restrict__ dw1, const float* __restrict__ db1,
    const float* __restrict__ dw2, const float* __restrict__ db2,
    const float* __restrict__ dw3, const float* __restrict__ db3,
    const float* __restrict__ tw1, const float* __restrict__ tb1,
    const float* __restrict__ tw2, const float* __restrict__ tb2,
    const float* __restrict__ Gm, const float* __restrict__ gv,
    const float* __restrict__ bbp,
    double* __restrict__ acc, float4* __restrict__ zbuf) {
    int i = blockIdx.x * 256 + threadIdx.x;
    bool active = (i < NSAMP);
    int row = active ? i : 0;
    const float4* xr = (const float4*)(x1 + (size_t)row * 128);

    float u[16], v[16];
#pragma unroll
    for (int k = 0; k < 16; ++k) { u[k] = 0.f; v[k] = 0.f; }
    float s2 = 0.f, sb = 0.f;

    float4 buf[4];
#pragma unroll
    for (int c = 0; c < 4; ++c) buf[c] = xr[c];

#pragma unroll 1
    for (int blk = 0; blk < 8; ++blk) {
        float xe[16];
#pragma unroll
        for (int c = 0; c < 4; ++c) {
            xe[c * 4 + 0] = buf[c].x; xe[c * 4 + 1] = buf[c].y;
            xe[c * 4 + 2] = buf[c].z; xe[c * 4 + 3] = buf[c].w;
        }
        if (blk < 7) {
#pragma unroll
            for (int c = 0; c < 4; ++c) buf[c] = xr[(blk + 1) * 4 + c];
        }
        int j0 = blk * 16;
#pragma unroll
        for (int e = 0; e < 16; ++e) {
            float x = xe[e];
            s2 = fmaf(x, x, s2);
            sb = fmaf(x, db3[j0 + e], sb);
#pragma unroll
            for (int k = 0; k < 16; ++k) u[k] = fmaf(x, ew1[(j0 + e) * 16 + k], u[k]);
        }
#pragma unroll
        for (int q = 0; q < 16; ++q) {
            float a2 = v[q];
#pragma unroll
            for (int e = 0; e < 16; ++e) a2 = fmaf(xe[e], dw3[q * 128 + j0 + e], a2);
            v[q] = a2;
        }
    }

    // encoder tail
    float h1[16];
#pragma unroll
    for (int k = 0; k < 16; ++k) h1[k] = ftanh(u[k] + eb1[k]);
    float h2[8];
#pragma unroll
    for (int m = 0; m < 8; ++m) {
        float a2 = eb2[m];
#pragma unroll
        for (int k = 0; k < 16; ++k) a2 = fmaf(h1[k], ew2[k * 8 + m], a2);
        h2[m] = ftanh(a2);
    }
    float a3 = eb3[0];
#pragma unroll
    for (int m = 0; m < 8; ++m) a3 = fmaf(h2[m], ew3[m], a3);
    float z1 = ftanh(a3);

    // decoder (x2 never materialized)
    float d1[8];
#pragma unroll
    for (int p = 0; p < 8; ++p) d1[p] = ftanh(fmaf(z1, dw1[p], db1[p]));
    float d2[16];
#pragma unroll
    for (int q = 0; q < 16; ++q) {
        float a2 = db2[q];
#pragma unroll
        for (int p = 0; p < 8; ++p) a2 = fmaf(d1[p], dw2[p * 16 + q], a2);
        d2[q] = ftanh(a2);
    }

    // distances via precomputed Gram
    float dot = sb;
#pragma unroll
    for (int q = 0; q < 16; ++q) dot = fmaf(d2[q], v[q], dot);
    float n2 = *bbp;
#pragma unroll
    for (int a = 0; a < 16; ++a) {
        float ra = 2.0f * gv[a];
#pragma unroll
        for (int b = 0; b < 16; ++b) ra = fmaf(Gm[a * 16 + b], d2[b], ra);
        n2 = fmaf(d2[a], ra, n2);
    }
    n2 = fmaxf(n2, 1e-20f);
    float euc2 = fmaxf(s2 - 2.0f * dot + n2, 0.f);
    float deuc = sqrtf(euc2);
    float dcos = dot * rsqrtf(s2 * n2);

    float zf[3] = {z1, dcos, deuc};

    // estimator
    float e1[8];
#pragma unroll
    for (int p = 0; p < 8; ++p) {
        float a2 = tb1[p];
        a2 = fmaf(zf[0], tw1[0 * 8 + p], a2);
        a2 = fmaf(zf[1], tw1[1 * 8 + p], a2);
        a2 = fmaf(zf[2], tw1[2 * 8 + p], a2);
        e1[p] = ftanh(a2);
    }
    float lg[4];
#pragma unroll
    for (int k = 0; k < 4; ++k) {
        float a2 = tb2[k];
#pragma unroll
        for (int p = 0; p < 8; ++p) a2 = fmaf(e1[p], tw2[p * 4 + k], a2);
        lg[k] = a2;
    }
    float mx = fmaxf(fmaxf(lg[0], lg[1]), fmaxf(lg[2], lg[3]));
    float ex[4]; float se = 0.f;
#pragma unroll
    for (int k = 0; k < 4; ++k) { ex[k] = __expf(lg[k] - mx); se += ex[k]; }
    float inv = __fdividef(1.0f, se);
    float gam[4];
#pragma unroll
    for (int k = 0; k < 4; ++k) gam[k] = ex[k] * inv;

    if (active) zbuf[i] = make_float4(zf[0], zf[1], zf[2], 0.f);
    if (!active) { gam[0] = gam[1] = gam[2] = gam[3] = 0.f; euc2 = 0.f; }

    // block reduction of 41 moment values
    __shared__ float sPart[4][41];
    int lane = threadIdx.x & 63;
    int wid = threadIdx.x >> 6;

#define REDUCE_STORE(T, VAL) { float _v = (VAL);                          \
        _v += __shfl_down(_v, 32); _v += __shfl_down(_v, 16);             \
        _v += __shfl_down(_v, 8);  _v += __shfl_down(_v, 4);              \
        _v += __shfl_down(_v, 2);  _v += __shfl_down(_v, 1);              \
        if (lane == 0) sPart[wid][T] = _v; }

#pragma unroll
    for (int k = 0; k < 4; ++k) REDUCE_STORE(k, gam[k]);
#pragma unroll
    for (int k = 0; k < 4; ++k) {
#pragma unroll
        for (int d = 0; d < 3; ++d) REDUCE_STORE(4 + k * 3 + d, gam[k] * zf[d]);
    }
#pragma unroll
    for (int k = 0; k < 4; ++k) {
        REDUCE_STORE(16 + k * 6 + 0, gam[k] * zf[0] * zf[0]);
        REDUCE_STORE(16 + k * 6 + 1, gam[k] * zf[0] * zf[1]);
        REDUCE_STORE(16 + k * 6 + 2, gam[k] * zf[0] * zf[2]);
        REDUCE_STORE(16 + k * 6 + 3, gam[k] * zf[1] * zf[1]);
        REDUCE_STORE(16 + k * 6 + 4, gam[k] * zf[1] * zf[2]);
        REDUCE_STORE(16 + k * 6 + 5, gam[k] * zf[2] * zf[2]);
    }
    REDUCE_STORE(40, euc2);
#undef REDUCE_STORE

    __syncthreads();
    if (threadIdx.x < 41) {
        double s = (double)sPart[0][threadIdx.x] + (double)sPart[1][threadIdx.x]
                 + (double)sPart[2][threadIdx.x] + (double)sPart[3][threadIdx.x];
        unsafeAtomicAdd(&acc[threadIdx.x], s);
    }
}

__global__ void gmm_kernel(double* __restrict__ acc, float* __restrict__ P) {
    if (threadIdx.x != 0 || blockIdx.x != 0) return;
    double M[6] = {0, 0, 0, 0, 0, 0}, bv[3] = {0, 0, 0}, A = 0.0, loss3 = 0.0;
    const double TWO_PI = 6.283185307179586;
    for (int k = 0; k < 4; ++k) {
        double g = acc[k];
        double phi = g / (double)NSAMP;
        double mu0 = acc[4 + k * 3 + 0] / g;
        double mu1 = acc[4 + k * 3 + 1] / g;
        double mu2 = acc[4 + k * 3 + 2] / g;
        double S00 = acc[16 + k * 6 + 0] / g - mu0 * mu0;
        double S01 = acc[16 + k * 6 + 1] / g - mu0 * mu1;
        double S02 = acc[16 + k * 6 + 2] / g - mu0 * mu2;
        double S11 = acc[16 + k * 6 + 3] / g - mu1 * mu1;
        double S12 = acc[16 + k * 6 + 4] / g - mu1 * mu2;
        double S22 = acc[16 + k * 6 + 5] / g - mu2 * mu2;
        double c00 = S11 * S22 - S12 * S12;
        double c01 = S02 * S12 - S01 * S22;
        double c02 = S01 * S12 - S02 * S11;
        double det = S00 * c00 + S01 * c01 + S02 * c02;
        double id = 1.0 / det;
        double I00 = c00 * id, I01 = c01 * id, I02 = c02 * id;
        double I11 = (S00 * S22 - S02 * S02) * id;
        double I12 = (S01 * S02 - S00 * S12) * id;
        double I22 = (S00 * S11 - S01 * S01) * id;
        M[0] += I00; M[1] += I01; M[2] += I02; M[3] += I11; M[4] += I12; M[5] += I22;
        double b0 = I00 * mu0 + I01 * mu1 + I02 * mu2;
        double b1 = I01 * mu0 + I11 * mu1 + I12 * mu2;
        double b2 = I02 * mu0 + I12 * mu1 + I22 * mu2;
        bv[0] += b0; bv[1] += b1; bv[2] += b2;
        double quad = mu0 * b0 + mu1 * b1 + mu2 * b2;
        A += -log(phi) + 0.5 * log(TWO_PI * TWO_PI * TWO_PI * det) + 0.5 * quad;
        loss3 += 1e-4 * (1.0 / S00 + 1.0 / S11 + 1.0 / S22);
    }
    P[0] = (float)M[0]; P[1] = (float)M[1]; P[2] = (float)M[2];
    P[3] = (float)M[3]; P[4] = (float)M[4]; P[5] = (float)M[5];
    P[6] = (float)bv[0]; P[7] = (float)bv[1]; P[8] = (float)bv[2];
    P[9] = (float)A;
    acc[42] = acc[40] / (double)NSAMP + loss3;   // loss1 + loss3
}

__global__ __launch_bounds__(256) void energy_kernel(const float4* __restrict__ zbuf,
                                                     const float* __restrict__ P,
                                                     double* __restrict__ acc,
                                                     float* __restrict__ out) {
    int i = blockIdx.x * 256 + threadIdx.x;
    float e = 0.f;
    if (i < NSAMP) {
        float4 z4 = zbuf[i];
        float z0 = z4.x, z1 = z4.y, z2 = z4.z;
        float q = P[0] * z0 * z0 + P[3] * z1 * z1 + P[5] * z2 * z2
                + 2.f * (P[1] * z0 * z1 + P[2] * z0 * z2 + P[4] * z1 * z2);
        e = P[9] + 0.5f * q - (P[6] * z0 + P[7] * z1 + P[8] * z2);
        out[i] = e;
    }
    float s = e;
    s += __shfl_down(s, 32); s += __shfl_down(s, 16); s += __shfl_down(s, 8);
    s += __shfl_down(s, 4);  s += __shfl_down(s, 2);  s += __shfl_down(s, 1);
    __shared__ float sE[4];
    if ((threadIdx.x & 63) == 0) sE[threadIdx.x >> 6] = s;
    __syncthreads();
    if (threadIdx.x == 0) {
        double t = (double)sE[0] + (double)sE[1] + (double)sE[2] + (double)sE[3];
        unsafeAtomicAdd(&acc[41], t);
    }
}

__global__ void final_kernel(const double* __restrict__ acc, float* __restrict__ out) {
    if (threadIdx.x == 0 && blockIdx.x == 0)
        out[NSAMP] = (float)(acc[42] + 0.01 * acc[41] / (double)NSAMP);
}

extern "C" void kernel_launch(void* const* d_in, const int* in_sizes, int n_in,
                              void* d_out, int out_size, void* d_ws, size_t ws_size,
                              hipStream_t stream) {
    const float* x1  = (const float*)d_in[0];
    const float* ew1 = (const float*)d_in[1];
    const float* eb1 = (const float*)d_in[2];
    const float* ew2 = (const float*)d_in[3];
    const float* eb2 = (const float*)d_in[4];
    const float* ew3 = (const float*)d_in[5];
    const float* eb3 = (const float*)d_in[6];
    const float* dw1 = (const float*)d_in[7];
    const float* db1 = (const float*)d_in[8];
    const float* dw2 = (const float*)d_in[9];
    const float* db2 = (const float*)d_in[10];
    const float* dw3 = (const float*)d_in[11];
    const float* db3 = (const float*)d_in[12];
    const float* tw1 = (const float*)d_in[13];
    const float* tb1 = (const float*)d_in[14];
    const float* tw2 = (const float*)d_in[15];
    const float* tb2 = (const float*)d_in[16];
    float* out = (float*)d_out;
    char* ws = (char*)d_ws;
    double* acc = (double*)ws;
    float* P    = (float*)(ws + 384);
    float* Gm   = (float*)(ws + 1024);
    float* gv   = (float*)(ws + 2048);
    float* bb   = (float*)(ws + 2112);
    float4* zb  = (float4*)(ws + 4096);

    hipMemsetAsync(d_ws, 0, 512, stream);
    prep_kernel<<<1, 256, 0, stream>>>(dw3, db3, Gm, gv, bb);
    pass1_kernel<<<NBLK, 256, 0, stream>>>(x1, ew1, eb1, ew2, eb2, ew3, eb3,
                                           dw1, db1, dw2, db2, dw3, db3,
                                           tw1, tb1, tw2, tb2, Gm, gv, bb, acc, zb);
    gmm_kernel<<<1, 64, 0, stream>>>(acc, P);
    energy_kernel<<<NBLK, 256, 0, stream>>>(zb, P, acc, out);
    final_kernel<<<1, 64, 0, stream>>>(acc, out);
}